// Round 4
// baseline (377.502 us; speedup 1.0000x reference)
//
#include <hip/hip_runtime.h>
#include <hip/hip_bf16.h>

// GCN: 3x GraphConv(sum-agg) + ELU, mean-pool, linear head, log_softmax.
// N=50000, E=400000, G=64, D_IN=200, D_HID=32. All float inputs fp32.
// Restructure: segment_sum(x[src]) @ Wr == segment_sum((x@Wr)[src]) -> matmul
// first (200->32), aggregate 32-wide rows via CSR pull (no float atomics).
// R3: gemm computes both r/l columns per x-read (halves LDS traffic, was
// LDS-BW bound); agg+gemm fused for layers 2,3 (h never hits global).

#define D_IN 200
#define D_HID 32
#define N_GRAPHS 64

#define SCAN_TILE 2048   // elements per scan block (256 thr x 8)
#define SCAN_ITEMS 8

// ---------------- CSR build ----------------
__global__ void count_edges(const int* __restrict__ dst, int* __restrict__ cnt, int E) {
    int e = blockIdx.x * blockDim.x + threadIdx.x;
    if (e < E) atomicAdd(&cnt[dst[e]], 1);
}

__global__ void scan_partial(const int* __restrict__ cnt, int* __restrict__ partial, int N) {
    __shared__ int sdata[256];
    int t = threadIdx.x;
    int base = blockIdx.x * SCAN_TILE + t * SCAN_ITEMS;
    int s = 0;
#pragma unroll
    for (int i = 0; i < SCAN_ITEMS; ++i) {
        int idx = base + i;
        if (idx < N) s += cnt[idx];
    }
    sdata[t] = s;
    __syncthreads();
    for (int off = 128; off > 0; off >>= 1) {
        if (t < off) sdata[t] += sdata[t + off];
        __syncthreads();
    }
    if (t == 0) partial[blockIdx.x] = sdata[0];
}

__global__ void scan_offsets(int* __restrict__ partial, int numBlocks) {
    if (threadIdx.x == 0) {
        int run = 0;
        for (int i = 0; i < numBlocks; ++i) { int v = partial[i]; partial[i] = run; run += v; }
    }
}

__global__ void scan_final(const int* __restrict__ cnt, const int* __restrict__ partial,
                           int* __restrict__ row_ptr, int* __restrict__ cursor, int N) {
    __shared__ int sdata[256];
    int t = threadIdx.x;
    int base = blockIdx.x * SCAN_TILE + t * SCAN_ITEMS;
    int vals[SCAN_ITEMS];
    int s = 0;
#pragma unroll
    for (int i = 0; i < SCAN_ITEMS; ++i) {
        int idx = base + i;
        vals[i] = (idx < N) ? cnt[idx] : 0;
        s += vals[i];
    }
    sdata[t] = s;
    __syncthreads();
    int sum = s;
    for (int off = 1; off < 256; off <<= 1) {
        int v = (t >= off) ? sdata[t - off] : 0;
        __syncthreads();
        sdata[t] += v;
        __syncthreads();
    }
    int run = partial[blockIdx.x] + sdata[t] - sum;
#pragma unroll
    for (int i = 0; i < SCAN_ITEMS; ++i) {
        int idx = base + i;
        if (idx < N) { row_ptr[idx] = run; cursor[idx] = run; run += vals[i]; }
    }
    if (blockIdx.x == gridDim.x - 1 && t == 255) row_ptr[N] = partial[blockIdx.x] + sdata[255];
}

__global__ void fill_csr(const int* __restrict__ src, const int* __restrict__ dst,
                         int* __restrict__ cursor, int* __restrict__ colIdx, int E) {
    int e = blockIdx.x * blockDim.x + threadIdx.x;
    if (e < E) {
        int p = atomicAdd(&cursor[dst[e]], 1);
        colIdx[p] = src[e];
    }
}

// ---------------- GEMM: X (N x K) @ [Wr | Wl] -> yr, yl (N x 32 each) ----------------
// 64 nodes/block. Thread = (col c = t&31, node-group t>>5 of 8 nodes), computes
// BOTH the Wr and Wl column -> each staged x float4 feeds 8 FMAs (LDS traffic
// halved vs 1-col layout; now VALU-bound). Staging is a linear float4 copy.
template <int K>
__global__ __launch_bounds__(256) void gemm_xw(const float* __restrict__ X,
                                               const float* __restrict__ Wr,
                                               const float* __restrict__ Wl,
                                               float* __restrict__ yr, float* __restrict__ yl,
                                               int N) {
    constexpr int K4 = K / 4;
    __shared__ float4 xs[64 * K4];   // K=200: 51.2 KB -> 3 blocks/CU
    int t = threadIdx.x;
    long base = (long)blockIdx.x * 64;
    const float4* X4 = (const float4*)X;
    long total4 = (long)N * K4;
    long g0 = base * K4;
    for (int i = t; i < 64 * K4; i += 256) {
        long gi = g0 + i;
        xs[i] = (gi < total4) ? X4[gi] : make_float4(0.f, 0.f, 0.f, 0.f);
    }
    __syncthreads();

    int c = t & 31;
    int nb = (t >> 5) * 8;
    float accr[8] = {0.f, 0.f, 0.f, 0.f, 0.f, 0.f, 0.f, 0.f};
    float accl[8] = {0.f, 0.f, 0.f, 0.f, 0.f, 0.f, 0.f, 0.f};
    for (int k4 = 0; k4 < K4; ++k4) {
        float wr[4], wl[4];
#pragma unroll
        for (int q = 0; q < 4; ++q) {
            wr[q] = Wr[(k4 * 4 + q) * 32 + c];
            wl[q] = Wl[(k4 * 4 + q) * 32 + c];
        }
#pragma unroll
        for (int i = 0; i < 8; ++i) {
            float4 xv = xs[(nb + i) * K4 + k4];
            accr[i] += xv.x * wr[0] + xv.y * wr[1] + xv.z * wr[2] + xv.w * wr[3];
            accl[i] += xv.x * wl[0] + xv.y * wl[1] + xv.z * wl[2] + xv.w * wl[3];
        }
    }
#pragma unroll
    for (int i = 0; i < 8; ++i) {
        long node = base + nb + i;
        if (node < N) {
            yr[node * 32 + c] = accr[i];
            yl[node * 32 + c] = accl[i];
        }
    }
}

__device__ __forceinline__ float4 elu4(float4 v) {
    float4 o;
    o.x = (v.x > 0.f) ? v.x : expm1f(v.x);
    o.y = (v.y > 0.f) ? v.y : expm1f(v.y);
    o.z = (v.z > 0.f) ? v.z : expm1f(v.z);
    o.w = (v.w > 0.f) ? v.w : expm1f(v.w);
    return o;
}

// ---------------- fused: agg(layer i) + ELU -> LDS tile -> gemm (layer i+1, K=32) ----
__global__ __launch_bounds__(256) void agg_gemm32(const float4* __restrict__ yin_r,
                                                  const float4* __restrict__ yin_l,
                                                  const int* __restrict__ row_ptr,
                                                  const int* __restrict__ colIdx,
                                                  const float* __restrict__ b,
                                                  const float* __restrict__ Wr,
                                                  const float* __restrict__ Wl,
                                                  float* __restrict__ yr_out,
                                                  float* __restrict__ yl_out, int N) {
    __shared__ float4 hs[64 * 8];   // 8 KB h-tile
    int t = threadIdx.x;
    int base = blockIdx.x * 64;
    int f4 = t & 7;
    int slot = t >> 3;              // 0..31, handles nodes slot and slot+32
    float4 b4 = ((const float4*)b)[f4];
#pragma unroll
    for (int half = 0; half < 2; ++half) {
        int ln = slot + half * 32;
        int node = base + ln;
        float4 o = make_float4(0.f, 0.f, 0.f, 0.f);
        if (node < N) {
            int s = row_ptr[node], e = row_ptr[node + 1];
            float ax = 0.f, ay = 0.f, az = 0.f, aw = 0.f;
            for (int p = s; p < e; ++p) {
                int j = colIdx[p];
                float4 v = yin_r[(long)j * 8 + f4];
                ax += v.x; ay += v.y; az += v.z; aw += v.w;
            }
            float4 rv = yin_l[(long)node * 8 + f4];
            o = elu4(make_float4(ax + b4.x + rv.x, ay + b4.y + rv.y,
                                 az + b4.z + rv.z, aw + b4.w + rv.w));
        }
        hs[ln * 8 + f4] = o;
    }
    __syncthreads();

    int c = t & 31;
    int nb = (t >> 5) * 8;
    float accr[8] = {0.f, 0.f, 0.f, 0.f, 0.f, 0.f, 0.f, 0.f};
    float accl[8] = {0.f, 0.f, 0.f, 0.f, 0.f, 0.f, 0.f, 0.f};
    for (int k4 = 0; k4 < 8; ++k4) {
        float wr[4], wl[4];
#pragma unroll
        for (int q = 0; q < 4; ++q) {
            wr[q] = Wr[(k4 * 4 + q) * 32 + c];
            wl[q] = Wl[(k4 * 4 + q) * 32 + c];
        }
#pragma unroll
        for (int i = 0; i < 8; ++i) {
            float4 xv = hs[(nb + i) * 8 + k4];
            accr[i] += xv.x * wr[0] + xv.y * wr[1] + xv.z * wr[2] + xv.w * wr[3];
            accl[i] += xv.x * wl[0] + xv.y * wl[1] + xv.z * wl[2] + xv.w * wl[3];
        }
    }
#pragma unroll
    for (int i = 0; i < 8; ++i) {
        long node = (long)base + nb + i;
        if (node < N) {
            yr_out[node * 32 + c] = accr[i];
            yl_out[node * 32 + c] = accl[i];
        }
    }
}

// ---------------- layer-3 agg + ELU -> global h ----------------
__global__ __launch_bounds__(256) void agg_elu(const float4* __restrict__ yin_r,
                                               const float4* __restrict__ yin_l,
                                               const int* __restrict__ row_ptr,
                                               const int* __restrict__ colIdx,
                                               const float* __restrict__ b,
                                               float4* __restrict__ hout, int N) {
    int t = threadIdx.x;
    int base = blockIdx.x * 64;
    int f4 = t & 7;
    int slot = t >> 3;
    float4 b4 = ((const float4*)b)[f4];
#pragma unroll
    for (int half = 0; half < 2; ++half) {
        int node = base + slot + half * 32;
        if (node >= N) continue;
        int s = row_ptr[node], e = row_ptr[node + 1];
        float ax = 0.f, ay = 0.f, az = 0.f, aw = 0.f;
        for (int p = s; p < e; ++p) {
            int j = colIdx[p];
            float4 v = yin_r[(long)j * 8 + f4];
            ax += v.x; ay += v.y; az += v.z; aw += v.w;
        }
        float4 rv = yin_l[(long)node * 8 + f4];
        hout[(long)node * 8 + f4] = elu4(make_float4(ax + b4.x + rv.x, ay + b4.y + rv.y,
                                                     az + b4.z + rv.z, aw + b4.w + rv.w));
    }
}

// ---------------- global mean pool (batch is sorted) ----------------
__global__ void pool_kernel(const float4* __restrict__ h4, const int* __restrict__ batch,
                            float* __restrict__ pooled, int N) {
    int g = blockIdx.x;
    int lo = 0, hi = N;
    while (lo < hi) { int mid = (lo + hi) >> 1; if (batch[mid] < g) lo = mid + 1; else hi = mid; }
    int start = lo;
    hi = N;
    while (lo < hi) { int mid = (lo + hi) >> 1; if (batch[mid] < g + 1) lo = mid + 1; else hi = mid; }
    int end = lo;

    int f4 = threadIdx.x & 7, r = threadIdx.x >> 3;  // 32 row-lanes x 8 feat4
    float4 acc = make_float4(0.f, 0.f, 0.f, 0.f);
    for (int i = start + r; i < end; i += 32) {
        float4 v = h4[(long)i * 8 + f4];
        acc.x += v.x; acc.y += v.y; acc.z += v.z; acc.w += v.w;
    }
    __shared__ float4 red[32][8];
    red[r][f4] = acc;
    __syncthreads();
    if (r == 0) {
        float4 s = make_float4(0.f, 0.f, 0.f, 0.f);
#pragma unroll
        for (int r2 = 0; r2 < 32; ++r2) {
            float4 v = red[r2][f4];
            s.x += v.x; s.y += v.y; s.z += v.z; s.w += v.w;
        }
        float inv = 1.f / fmaxf((float)(end - start), 1.f);
        pooled[g * 32 + f4 * 4 + 0] = s.x * inv;
        pooled[g * 32 + f4 * 4 + 1] = s.y * inv;
        pooled[g * 32 + f4 * 4 + 2] = s.z * inv;
        pooled[g * 32 + f4 * 4 + 3] = s.w * inv;
    }
}

// ---------------- linear head + log_softmax ----------------
__global__ void head_kernel(const float* __restrict__ pooled,
                            const float* __restrict__ Wlin,
                            const float* __restrict__ blin,
                            float* __restrict__ out) {
    int g = threadIdx.x;
    if (g >= N_GRAPHS) return;
    float c0 = blin[0];
    float c1 = blin[1];
    for (int k = 0; k < 32; ++k) {
        float p = pooled[g * 32 + k];
        c0 += p * Wlin[k * 2 + 0];
        c1 += p * Wlin[k * 2 + 1];
    }
    float m = fmaxf(c0, c1);
    float lse = m + logf(expf(c0 - m) + expf(c1 - m));
    out[g * 2 + 0] = c0 - lse;
    out[g * 2 + 1] = c1 - lse;
}

extern "C" void kernel_launch(void* const* d_in, const int* in_sizes, int n_in,
                              void* d_out, int out_size, void* d_ws, size_t ws_size,
                              hipStream_t stream) {
    const float* x     = (const float*)d_in[0];
    const int*   eidx  = (const int*)d_in[1];
    const int*   batch = (const int*)d_in[3];
    const float* W1r = (const float*)d_in[4];
    const float* W1l = (const float*)d_in[5];
    const float* b1  = (const float*)d_in[6];
    const float* W2r = (const float*)d_in[7];
    const float* W2l = (const float*)d_in[8];
    const float* b2  = (const float*)d_in[9];
    const float* W3r = (const float*)d_in[10];
    const float* W3l = (const float*)d_in[11];
    const float* b3  = (const float*)d_in[12];
    const float* Wlin = (const float*)d_in[13];
    const float* blin = (const float*)d_in[14];
    float* out = (float*)d_out;

    const int N = in_sizes[0] / D_IN;  // 50000
    const int E = in_sizes[1] / 2;     // 400000
    const int* src = eidx;
    const int* dst = eidx + E;

    char* w = (char*)d_ws;
    auto alloc = [&](size_t bytes) -> void* {
        void* p = (void*)w;
        w += (bytes + 255) & ~(size_t)255;
        return p;
    };
    int*   cnt     = (int*)alloc((size_t)N * 4);
    int*   row_ptr = (int*)alloc((size_t)(N + 1) * 4);
    int*   cursor  = (int*)alloc((size_t)(N + 1) * 4);
    int*   colIdx  = (int*)alloc((size_t)E * 4);
    int*   partial = (int*)alloc((size_t)256 * 4);
    float* yrA     = (float*)alloc((size_t)N * 32 * 4);
    float* ylA     = (float*)alloc((size_t)N * 32 * 4);
    float* yrB     = (float*)alloc((size_t)N * 32 * 4);
    float* ylB     = (float*)alloc((size_t)N * 32 * 4);
    float* pooled  = (float*)alloc((size_t)N_GRAPHS * 32 * 4);

    // --- CSR build ---
    hipMemsetAsync(cnt, 0, (size_t)N * 4, stream);
    int egrid = (E + 255) / 256;
    int sgrid = (N + SCAN_TILE - 1) / SCAN_TILE;  // 25
    count_edges<<<egrid, 256, 0, stream>>>(dst, cnt, E);
    scan_partial<<<sgrid, 256, 0, stream>>>(cnt, partial, N);
    scan_offsets<<<1, 64, 0, stream>>>(partial, sgrid);
    scan_final<<<sgrid, 256, 0, stream>>>(cnt, partial, row_ptr, cursor, N);
    fill_csr<<<egrid, 256, 0, stream>>>(src, dst, cursor, colIdx, E);

    int ngrid = (N + 63) / 64;  // 782

    // layer 1 gemm: x @ [W1r|W1l] -> yrA, ylA
    gemm_xw<D_IN><<<ngrid, 256, 0, stream>>>(x, W1r, W1l, yrA, ylA, N);
    // agg1 + ELU + gemm2 -> yrB, ylB
    agg_gemm32<<<ngrid, 256, 0, stream>>>((const float4*)yrA, (const float4*)ylA,
                                          row_ptr, colIdx, b1, W2r, W2l, yrB, ylB, N);
    // agg2 + ELU + gemm3 -> yrA, ylA
    agg_gemm32<<<ngrid, 256, 0, stream>>>((const float4*)yrB, (const float4*)ylB,
                                          row_ptr, colIdx, b2, W3r, W3l, yrA, ylA, N);
    // agg3 + ELU -> h3 (reuse yrB)
    agg_elu<<<ngrid, 256, 0, stream>>>((const float4*)yrA, (const float4*)ylA,
                                       row_ptr, colIdx, b3, (float4*)yrB, N);

    pool_kernel<<<N_GRAPHS, 256, 0, stream>>>((const float4*)yrB, batch, pooled, N);
    head_kernel<<<1, 64, 0, stream>>>(pooled, Wlin, blin, out);
}

// Round 5
// 260.490 us; speedup vs baseline: 1.4492x; 1.4492x over previous
//
#include <hip/hip_runtime.h>
#include <hip/hip_bf16.h>

// GCN: 3x GraphConv(sum-agg) + ELU, mean-pool, linear head, log_softmax.
// N=50000, E=400000, G=64, D_IN=200, D_HID=32. All float inputs fp32.
// segment_sum(x[src]) @ Wr == segment_sum((x@Wr)[src]) -> matmul first
// (200->32), aggregate 32-wide rows via CSR pull (no float atomics).
// R5: agg un-fused (VGPR~45 -> 8 waves/SIMD; R4's fused VGPR=160 -> 3 was a
// latency disaster), degree loop unrolled x4 for 4 outstanding gathers;
// gemm tiles 32 nodes (25.6KB LDS -> 6 blocks/CU); head fused into pool;
// scan_offsets folded into scan_final.

#define D_IN 200
#define D_HID 32
#define N_GRAPHS 64

#define SCAN_TILE 2048   // elements per scan block (256 thr x 8)
#define SCAN_ITEMS 8

// ---------------- CSR build ----------------
__global__ void count_edges(const int* __restrict__ dst, int* __restrict__ cnt, int E) {
    int e = blockIdx.x * blockDim.x + threadIdx.x;
    if (e < E) atomicAdd(&cnt[dst[e]], 1);
}

__global__ void scan_partial(const int* __restrict__ cnt, int* __restrict__ partial, int N) {
    __shared__ int sdata[256];
    int t = threadIdx.x;
    int base = blockIdx.x * SCAN_TILE + t * SCAN_ITEMS;
    int s = 0;
#pragma unroll
    for (int i = 0; i < SCAN_ITEMS; ++i) {
        int idx = base + i;
        if (idx < N) s += cnt[idx];
    }
    sdata[t] = s;
    __syncthreads();
    for (int off = 128; off > 0; off >>= 1) {
        if (t < off) sdata[t] += sdata[t + off];
        __syncthreads();
    }
    if (t == 0) partial[blockIdx.x] = sdata[0];
}

// Block-local exclusive scan + serial prefix of (<=25) block partials.
__global__ void scan_final(const int* __restrict__ cnt, const int* __restrict__ partial,
                           int* __restrict__ row_ptr, int* __restrict__ cursor, int N) {
    __shared__ int sdata[256];
    __shared__ int blockOff;
    int t = threadIdx.x;
    if (t == 0) {
        int run = 0;
        for (int i = 0; i < (int)blockIdx.x; ++i) run += partial[i];
        blockOff = run;
    }
    int base = blockIdx.x * SCAN_TILE + t * SCAN_ITEMS;
    int vals[SCAN_ITEMS];
    int s = 0;
#pragma unroll
    for (int i = 0; i < SCAN_ITEMS; ++i) {
        int idx = base + i;
        vals[i] = (idx < N) ? cnt[idx] : 0;
        s += vals[i];
    }
    sdata[t] = s;
    __syncthreads();
    int sum = s;
    for (int off = 1; off < 256; off <<= 1) {
        int v = (t >= off) ? sdata[t - off] : 0;
        __syncthreads();
        sdata[t] += v;
        __syncthreads();
    }
    int run = blockOff + sdata[t] - sum;
#pragma unroll
    for (int i = 0; i < SCAN_ITEMS; ++i) {
        int idx = base + i;
        if (idx < N) { row_ptr[idx] = run; cursor[idx] = run; run += vals[i]; }
    }
    if (blockIdx.x == gridDim.x - 1 && t == 255) row_ptr[N] = blockOff + sdata[255];
}

__global__ void fill_csr(const int* __restrict__ src, const int* __restrict__ dst,
                         int* __restrict__ cursor, int* __restrict__ colIdx, int E) {
    int e = blockIdx.x * blockDim.x + threadIdx.x;
    if (e < E) {
        int p = atomicAdd(&cursor[dst[e]], 1);
        colIdx[p] = src[e];
    }
}

// ---------------- GEMM: X (N x K) @ [Wr | Wl] -> yr, yl (N x 32 each) -------
// 32 nodes/block (K=200: 25.6KB LDS -> 6 blocks/CU). Thread = (col c=t&31,
// group t>>5 of 4 nodes), computes BOTH Wr and Wl columns per staged float4.
template <int K>
__global__ __launch_bounds__(256) void gemm_xw(const float* __restrict__ X,
                                               const float* __restrict__ Wr,
                                               const float* __restrict__ Wl,
                                               float* __restrict__ yr, float* __restrict__ yl,
                                               int N) {
    constexpr int K4 = K / 4;
    __shared__ float4 xs[32 * K4];
    int t = threadIdx.x;
    long base = (long)blockIdx.x * 32;
    const float4* X4 = (const float4*)X;
    long total4 = (long)N * K4;
    long g0 = base * K4;
    for (int i = t; i < 32 * K4; i += 256) {
        long gi = g0 + i;
        xs[i] = (gi < total4) ? X4[gi] : make_float4(0.f, 0.f, 0.f, 0.f);
    }
    __syncthreads();

    int c = t & 31;
    int nb = (t >> 5) * 4;   // 8 groups x 4 nodes = 32 nodes
    float accr[4] = {0.f, 0.f, 0.f, 0.f};
    float accl[4] = {0.f, 0.f, 0.f, 0.f};
    for (int k4 = 0; k4 < K4; ++k4) {
        float wr[4], wl[4];
#pragma unroll
        for (int q = 0; q < 4; ++q) {
            wr[q] = Wr[(k4 * 4 + q) * 32 + c];
            wl[q] = Wl[(k4 * 4 + q) * 32 + c];
        }
#pragma unroll
        for (int i = 0; i < 4; ++i) {
            float4 xv = xs[(nb + i) * K4 + k4];
            accr[i] += xv.x * wr[0] + xv.y * wr[1] + xv.z * wr[2] + xv.w * wr[3];
            accl[i] += xv.x * wl[0] + xv.y * wl[1] + xv.z * wl[2] + xv.w * wl[3];
        }
    }
#pragma unroll
    for (int i = 0; i < 4; ++i) {
        long node = base + nb + i;
        if (node < N) {
            yr[node * 32 + c] = accr[i];
            yl[node * 32 + c] = accl[i];
        }
    }
}

__device__ __forceinline__ float4 elu4(float4 v) {
    float4 o;
    o.x = (v.x > 0.f) ? v.x : expm1f(v.x);
    o.y = (v.y > 0.f) ? v.y : expm1f(v.y);
    o.z = (v.z > 0.f) ? v.z : expm1f(v.z);
    o.w = (v.w > 0.f) ? v.w : expm1f(v.w);
    return o;
}

// ---------------- aggregate (CSR pull) + bias + root + ELU -------------------
// 8 lanes/node (float4 each), 32 nodes/block. Degree loop unrolled x4: four
// independent colIdx loads + four independent dwordx4 gathers in flight per
// waitcnt round (~4x MLP on the latency chain). Low VGPR -> 8 waves/SIMD.
__global__ __launch_bounds__(256) void agg_elu_k(const float4* __restrict__ yin_r,
                                                 const float4* __restrict__ yin_l,
                                                 const int* __restrict__ row_ptr,
                                                 const int* __restrict__ colIdx,
                                                 const float* __restrict__ b,
                                                 float4* __restrict__ hout, int N) {
    int t = threadIdx.x;
    int f4 = t & 7;
    int node = blockIdx.x * 32 + (t >> 3);
    if (node >= N) return;
    int s = row_ptr[node], e = row_ptr[node + 1];
    // independent loads issued before the chain:
    float4 b4 = ((const float4*)b)[f4];
    float4 rv = yin_l[(long)node * 8 + f4];
    float ax = 0.f, ay = 0.f, az = 0.f, aw = 0.f;
    int p = s;
    for (; p + 4 <= e; p += 4) {
        int j0 = colIdx[p + 0];
        int j1 = colIdx[p + 1];
        int j2 = colIdx[p + 2];
        int j3 = colIdx[p + 3];
        float4 v0 = yin_r[(long)j0 * 8 + f4];
        float4 v1 = yin_r[(long)j1 * 8 + f4];
        float4 v2 = yin_r[(long)j2 * 8 + f4];
        float4 v3 = yin_r[(long)j3 * 8 + f4];
        ax += (v0.x + v1.x) + (v2.x + v3.x);
        ay += (v0.y + v1.y) + (v2.y + v3.y);
        az += (v0.z + v1.z) + (v2.z + v3.z);
        aw += (v0.w + v1.w) + (v2.w + v3.w);
    }
    for (; p < e; ++p) {
        int j = colIdx[p];
        float4 v = yin_r[(long)j * 8 + f4];
        ax += v.x; ay += v.y; az += v.z; aw += v.w;
    }
    hout[(long)node * 8 + f4] = elu4(make_float4(ax + b4.x + rv.x, ay + b4.y + rv.y,
                                                 az + b4.z + rv.z, aw + b4.w + rv.w));
}

// ---------------- global mean pool + linear head + log_softmax ---------------
// One block per graph (batch sorted). Head fused: logits/log_softmax are
// per-graph only.
__global__ void pool_head(const float4* __restrict__ h4, const int* __restrict__ batch,
                          const float* __restrict__ Wlin, const float* __restrict__ blin,
                          float* __restrict__ out, int N) {
    int g = blockIdx.x;
    int lo = 0, hi = N;
    while (lo < hi) { int mid = (lo + hi) >> 1; if (batch[mid] < g) lo = mid + 1; else hi = mid; }
    int start = lo;
    hi = N;
    while (lo < hi) { int mid = (lo + hi) >> 1; if (batch[mid] < g + 1) lo = mid + 1; else hi = mid; }
    int end = lo;

    int f4 = threadIdx.x & 7, r = threadIdx.x >> 3;  // 32 row-lanes x 8 feat4
    float4 acc = make_float4(0.f, 0.f, 0.f, 0.f);
    for (int i = start + r; i < end; i += 32) {
        float4 v = h4[(long)i * 8 + f4];
        acc.x += v.x; acc.y += v.y; acc.z += v.z; acc.w += v.w;
    }
    __shared__ float4 red[32][8];
    __shared__ float pooledS[32];
    red[r][f4] = acc;
    __syncthreads();
    if (r == 0) {
        float4 s = make_float4(0.f, 0.f, 0.f, 0.f);
#pragma unroll
        for (int r2 = 0; r2 < 32; ++r2) {
            float4 v = red[r2][f4];
            s.x += v.x; s.y += v.y; s.z += v.z; s.w += v.w;
        }
        float inv = 1.f / fmaxf((float)(end - start), 1.f);
        pooledS[f4 * 4 + 0] = s.x * inv;
        pooledS[f4 * 4 + 1] = s.y * inv;
        pooledS[f4 * 4 + 2] = s.z * inv;
        pooledS[f4 * 4 + 3] = s.w * inv;
    }
    __syncthreads();
    if (threadIdx.x == 0) {
        float c0 = blin[0], c1 = blin[1];
        for (int k = 0; k < 32; ++k) {
            float pk = pooledS[k];
            c0 += pk * Wlin[k * 2 + 0];
            c1 += pk * Wlin[k * 2 + 1];
        }
        float m = fmaxf(c0, c1);
        float lse = m + logf(expf(c0 - m) + expf(c1 - m));
        out[g * 2 + 0] = c0 - lse;
        out[g * 2 + 1] = c1 - lse;
    }
}

extern "C" void kernel_launch(void* const* d_in, const int* in_sizes, int n_in,
                              void* d_out, int out_size, void* d_ws, size_t ws_size,
                              hipStream_t stream) {
    const float* x     = (const float*)d_in[0];
    const int*   eidx  = (const int*)d_in[1];
    const int*   batch = (const int*)d_in[3];
    const float* W1r = (const float*)d_in[4];
    const float* W1l = (const float*)d_in[5];
    const float* b1  = (const float*)d_in[6];
    const float* W2r = (const float*)d_in[7];
    const float* W2l = (const float*)d_in[8];
    const float* b2  = (const float*)d_in[9];
    const float* W3r = (const float*)d_in[10];
    const float* W3l = (const float*)d_in[11];
    const float* b3  = (const float*)d_in[12];
    const float* Wlin = (const float*)d_in[13];
    const float* blin = (const float*)d_in[14];
    float* out = (float*)d_out;

    const int N = in_sizes[0] / D_IN;  // 50000
    const int E = in_sizes[1] / 2;     // 400000
    const int* src = eidx;
    const int* dst = eidx + E;

    char* w = (char*)d_ws;
    auto alloc = [&](size_t bytes) -> void* {
        void* p = (void*)w;
        w += (bytes + 255) & ~(size_t)255;
        return p;
    };
    int*   cnt     = (int*)alloc((size_t)N * 4);
    int*   row_ptr = (int*)alloc((size_t)(N + 1) * 4);
    int*   cursor  = (int*)alloc((size_t)(N + 1) * 4);
    int*   colIdx  = (int*)alloc((size_t)E * 4);
    int*   partial = (int*)alloc((size_t)256 * 4);
    float* yrA     = (float*)alloc((size_t)N * 32 * 4);
    float* ylA     = (float*)alloc((size_t)N * 32 * 4);
    float* yrB     = (float*)alloc((size_t)N * 32 * 4);
    float* ylB     = (float*)alloc((size_t)N * 32 * 4);
    float* hA      = (float*)alloc((size_t)N * 32 * 4);

    // --- CSR build ---
    hipMemsetAsync(cnt, 0, (size_t)N * 4, stream);
    int egrid = (E + 255) / 256;
    int sgrid = (N + SCAN_TILE - 1) / SCAN_TILE;  // 25
    count_edges<<<egrid, 256, 0, stream>>>(dst, cnt, E);
    scan_partial<<<sgrid, 256, 0, stream>>>(cnt, partial, N);
    scan_final<<<sgrid, 256, 0, stream>>>(cnt, partial, row_ptr, cursor, N);
    fill_csr<<<egrid, 256, 0, stream>>>(src, dst, cursor, colIdx, E);

    int ngrid = (N + 31) / 32;  // 1563

    // layer 1
    gemm_xw<D_IN><<<ngrid, 256, 0, stream>>>(x, W1r, W1l, yrA, ylA, N);
    agg_elu_k<<<ngrid, 256, 0, stream>>>((const float4*)yrA, (const float4*)ylA,
                                         row_ptr, colIdx, b1, (float4*)hA, N);
    // layer 2
    gemm_xw<D_HID><<<ngrid, 256, 0, stream>>>(hA, W2r, W2l, yrB, ylB, N);
    agg_elu_k<<<ngrid, 256, 0, stream>>>((const float4*)yrB, (const float4*)ylB,
                                         row_ptr, colIdx, b2, (float4*)hA, N);
    // layer 3
    gemm_xw<D_HID><<<ngrid, 256, 0, stream>>>(hA, W3r, W3l, yrA, ylA, N);
    agg_elu_k<<<ngrid, 256, 0, stream>>>((const float4*)yrA, (const float4*)ylA,
                                         row_ptr, colIdx, b3, (float4*)hA, N);

    pool_head<<<N_GRAPHS, 256, 0, stream>>>((const float4*)hA, batch, Wlin, blin, out, N);
}

// Round 6
// 236.298 us; speedup vs baseline: 1.5976x; 1.1024x over previous
//
#include <hip/hip_runtime.h>
#include <hip/hip_bf16.h>

// GCN: 3x GraphConv(sum-agg) + ELU, mean-pool, linear head, log_softmax.
// N=50000, E=400000, G=64, D_IN=200, D_HID=32. fp32 inputs/outputs.
// segment_sum(x[src]) @ Wr == segment_sum((x@Wr)[src]) -> matmul first
// (200->32), aggregate 32-wide rows via CSR pull (no float atomics).
// R6: layer-1 gemm via bf16 MFMA 16x16x32 (fp32 VALU outer-product was stuck
// at 49us with only 8us of real FMA: LDS broadcast redundancy + W-load
// overhead is structural). Layers 2/3 stay fp32 (error budget). Agg stays
// un-fused low-VGPR x4-unrolled (R5 win).

#define D_IN 200
#define D_HID 32
#define N_GRAPHS 64

#define KP 232            // padded K for bf16 tiles (200 -> 224 used, stride 232)
#define KB 7              // 7 k-blocks of 32
#define WT_ELEMS (64 * KP)       // 14848 bf16
#define WT_CHUNK16 (WT_ELEMS / 8)  // 1856 16B-chunks

#define SCAN_TILE 2048
#define SCAN_ITEMS 8

typedef __attribute__((ext_vector_type(8))) short bf16x8;
typedef __attribute__((ext_vector_type(4))) float f32x4;

// ---------------- CSR build ----------------
__global__ void count_edges(const int* __restrict__ dst, int* __restrict__ cnt, int E) {
    int e = blockIdx.x * blockDim.x + threadIdx.x;
    if (e < E) atomicAdd(&cnt[dst[e]], 1);
}

__global__ void scan_partial(const int* __restrict__ cnt, int* __restrict__ partial, int N) {
    __shared__ int sdata[256];
    int t = threadIdx.x;
    int base = blockIdx.x * SCAN_TILE + t * SCAN_ITEMS;
    int s = 0;
#pragma unroll
    for (int i = 0; i < SCAN_ITEMS; ++i) {
        int idx = base + i;
        if (idx < N) s += cnt[idx];
    }
    sdata[t] = s;
    __syncthreads();
    for (int off = 128; off > 0; off >>= 1) {
        if (t < off) sdata[t] += sdata[t + off];
        __syncthreads();
    }
    if (t == 0) partial[blockIdx.x] = sdata[0];
}

__global__ void scan_final(const int* __restrict__ cnt, const int* __restrict__ partial,
                           int* __restrict__ row_ptr, int* __restrict__ cursor, int N) {
    __shared__ int sdata[256];
    __shared__ int blockOff;
    int t = threadIdx.x;
    if (t == 0) {
        int run = 0;
        for (int i = 0; i < (int)blockIdx.x; ++i) run += partial[i];
        blockOff = run;
    }
    int base = blockIdx.x * SCAN_TILE + t * SCAN_ITEMS;
    int vals[SCAN_ITEMS];
    int s = 0;
#pragma unroll
    for (int i = 0; i < SCAN_ITEMS; ++i) {
        int idx = base + i;
        vals[i] = (idx < N) ? cnt[idx] : 0;
        s += vals[i];
    }
    sdata[t] = s;
    __syncthreads();
    int sum = s;
    for (int off = 1; off < 256; off <<= 1) {
        int v = (t >= off) ? sdata[t - off] : 0;
        __syncthreads();
        sdata[t] += v;
        __syncthreads();
    }
    int run = blockOff + sdata[t] - sum;
#pragma unroll
    for (int i = 0; i < SCAN_ITEMS; ++i) {
        int idx = base + i;
        if (idx < N) { row_ptr[idx] = run; cursor[idx] = run; run += vals[i]; }
    }
    if (blockIdx.x == gridDim.x - 1 && t == 255) row_ptr[N] = blockOff + sdata[255];
}

__global__ void fill_csr(const int* __restrict__ src, const int* __restrict__ dst,
                         int* __restrict__ cursor, int* __restrict__ colIdx, int E) {
    int e = blockIdx.x * blockDim.x + threadIdx.x;
    if (e < E) {
        int p = atomicAdd(&cursor[dst[e]], 1);
        colIdx[p] = src[e];
    }
}

// ---------------- pack [W1r|W1l] -> bf16 Wt[64][KP] (transposed, zero-padded) ----
__global__ void prep_w(const float* __restrict__ Wr, const float* __restrict__ Wl,
                       __hip_bfloat16* __restrict__ Wt) {
    int idx = blockIdx.x * blockDim.x + threadIdx.x;
    if (idx >= WT_ELEMS) return;
    int n = idx / KP, k = idx % KP;
    float v = 0.f;
    if (k < D_IN) v = (n < 32) ? Wr[k * 32 + n] : Wl[k * 32 + (n - 32)];
    Wt[idx] = __float2bfloat16(v);
}

// ---------------- layer-1 GEMM via MFMA: X(Nx200) @ [Wr|Wl] -> yr,yl (Nx32) ----
// 64-node tile. Stage x rows fp32->bf16 into LDS (stride KP=232, 16B-aligned);
// Wt staged by flat 16B copy. 4 waves x (16 rows x 64 cols); 7 MFMA per n-sub.
// A-frag: lane holds A[m=lane&15][k=(lane>>4)*8+j]; B likewise (Wt is [n][k]);
// C/D: col=lane&15, row=(lane>>4)*4+reg.
__global__ __launch_bounds__(256) void gemm_mfma(const float* __restrict__ X,
                                                 const __hip_bfloat16* __restrict__ Wt,
                                                 float* __restrict__ yr,
                                                 float* __restrict__ yl, int N) {
    __shared__ __hip_bfloat16 xs[64 * KP];
    __shared__ __hip_bfloat16 wsh[64 * KP];
    int t = threadIdx.x;
    long base = (long)blockIdx.x * 64;

    // stage W (flat 16B copy)
    {
        const float4* src4 = (const float4*)Wt;
        float4* dst4 = (float4*)wsh;
        for (int i = t; i < WT_CHUNK16; i += 256) dst4[i] = src4[i];
    }
    // stage X: 64 rows x 29 chunks of 8 floats -> bf16
    for (int i = t; i < 64 * (KP / 8); i += 256) {
        int row = i / (KP / 8), c8 = i % (KP / 8);
        int k0 = c8 * 8;
        long node = base + row;
        union { __hip_bfloat16 h[8]; float4 v; } u;
        if (node < N && k0 + 8 <= D_IN) {
            const float4* xp = (const float4*)(X + node * D_IN + k0);
            float4 v0 = xp[0], v1 = xp[1];
            u.h[0] = __float2bfloat16(v0.x); u.h[1] = __float2bfloat16(v0.y);
            u.h[2] = __float2bfloat16(v0.z); u.h[3] = __float2bfloat16(v0.w);
            u.h[4] = __float2bfloat16(v1.x); u.h[5] = __float2bfloat16(v1.y);
            u.h[6] = __float2bfloat16(v1.z); u.h[7] = __float2bfloat16(v1.w);
        } else {
#pragma unroll
            for (int q = 0; q < 8; ++q) {
                int k = k0 + q;
                float v = (node < N && k < D_IN) ? X[node * D_IN + k] : 0.f;
                u.h[q] = __float2bfloat16(v);
            }
        }
        *(float4*)(&xs[row * KP + k0]) = u.v;
    }
    __syncthreads();

    int lane = t & 63;
    int wv = t >> 6;              // wave id: node rows wv*16 .. wv*16+15
    int l15 = lane & 15, q = lane >> 4;

    bf16x8 a[KB];
#pragma unroll
    for (int kb = 0; kb < KB; ++kb)
        a[kb] = *(const bf16x8*)(const void*)(&xs[(wv * 16 + l15) * KP + kb * 32 + q * 8]);

#pragma unroll
    for (int ns = 0; ns < 4; ++ns) {
        f32x4 acc = {0.f, 0.f, 0.f, 0.f};
#pragma unroll
        for (int kb = 0; kb < KB; ++kb) {
            bf16x8 b = *(const bf16x8*)(const void*)(&wsh[(ns * 16 + l15) * KP + kb * 32 + q * 8]);
            acc = __builtin_amdgcn_mfma_f32_16x16x32_bf16(a[kb], b, acc, 0, 0, 0);
        }
        int col = ns * 16 + l15;
        float* Y = (col < 32) ? yr : yl;
        int cc = col & 31;
#pragma unroll
        for (int r = 0; r < 4; ++r) {
            long node = base + wv * 16 + q * 4 + r;
            if (node < N) Y[node * 32 + cc] = acc[r];
        }
    }
}

// ---------------- fp32 GEMM (K=32) for layers 2,3 ----------------
template <int K>
__global__ __launch_bounds__(256) void gemm_xw(const float* __restrict__ X,
                                               const float* __restrict__ Wr,
                                               const float* __restrict__ Wl,
                                               float* __restrict__ yr, float* __restrict__ yl,
                                               int N) {
    constexpr int K4 = K / 4;
    __shared__ float4 xs[32 * K4];
    int t = threadIdx.x;
    long base = (long)blockIdx.x * 32;
    const float4* X4 = (const float4*)X;
    long total4 = (long)N * K4;
    long g0 = base * K4;
    for (int i = t; i < 32 * K4; i += 256) {
        long gi = g0 + i;
        xs[i] = (gi < total4) ? X4[gi] : make_float4(0.f, 0.f, 0.f, 0.f);
    }
    __syncthreads();

    int c = t & 31;
    int nb = (t >> 5) * 4;
    float accr[4] = {0.f, 0.f, 0.f, 0.f};
    float accl[4] = {0.f, 0.f, 0.f, 0.f};
    for (int k4 = 0; k4 < K4; ++k4) {
        float wr[4], wl[4];
#pragma unroll
        for (int qq = 0; qq < 4; ++qq) {
            wr[qq] = Wr[(k4 * 4 + qq) * 32 + c];
            wl[qq] = Wl[(k4 * 4 + qq) * 32 + c];
        }
#pragma unroll
        for (int i = 0; i < 4; ++i) {
            float4 xv = xs[(nb + i) * K4 + k4];
            accr[i] = fmaf(xv.x, wr[0], accr[i]); accr[i] = fmaf(xv.y, wr[1], accr[i]);
            accr[i] = fmaf(xv.z, wr[2], accr[i]); accr[i] = fmaf(xv.w, wr[3], accr[i]);
            accl[i] = fmaf(xv.x, wl[0], accl[i]); accl[i] = fmaf(xv.y, wl[1], accl[i]);
            accl[i] = fmaf(xv.z, wl[2], accl[i]); accl[i] = fmaf(xv.w, wl[3], accl[i]);
        }
    }
#pragma unroll
    for (int i = 0; i < 4; ++i) {
        long node = base + nb + i;
        if (node < N) {
            yr[node * 32 + c] = accr[i];
            yl[node * 32 + c] = accl[i];
        }
    }
}

__device__ __forceinline__ float4 elu4(float4 v) {
    float4 o;
    o.x = (v.x > 0.f) ? v.x : expm1f(v.x);
    o.y = (v.y > 0.f) ? v.y : expm1f(v.y);
    o.z = (v.z > 0.f) ? v.z : expm1f(v.z);
    o.w = (v.w > 0.f) ? v.w : expm1f(v.w);
    return o;
}

// ---------------- aggregate (CSR pull) + bias + root + ELU -------------------
// 8 lanes/node (float4 each), x4-unrolled degree loop (4 outstanding gathers),
// low VGPR -> 8 waves/SIMD (R5 config — worked).
__global__ __launch_bounds__(256) void agg_elu_k(const float4* __restrict__ yin_r,
                                                 const float4* __restrict__ yin_l,
                                                 const int* __restrict__ row_ptr,
                                                 const int* __restrict__ colIdx,
                                                 const float* __restrict__ b,
                                                 float4* __restrict__ hout, int N) {
    int t = threadIdx.x;
    int f4 = t & 7;
    int node = blockIdx.x * 32 + (t >> 3);
    if (node >= N) return;
    int s = row_ptr[node], e = row_ptr[node + 1];
    float4 b4 = ((const float4*)b)[f4];
    float4 rv = yin_l[(long)node * 8 + f4];
    float ax = 0.f, ay = 0.f, az = 0.f, aw = 0.f;
    int p = s;
    for (; p + 4 <= e; p += 4) {
        int j0 = colIdx[p + 0];
        int j1 = colIdx[p + 1];
        int j2 = colIdx[p + 2];
        int j3 = colIdx[p + 3];
        float4 v0 = yin_r[(long)j0 * 8 + f4];
        float4 v1 = yin_r[(long)j1 * 8 + f4];
        float4 v2 = yin_r[(long)j2 * 8 + f4];
        float4 v3 = yin_r[(long)j3 * 8 + f4];
        ax += (v0.x + v1.x) + (v2.x + v3.x);
        ay += (v0.y + v1.y) + (v2.y + v3.y);
        az += (v0.z + v1.z) + (v2.z + v3.z);
        aw += (v0.w + v1.w) + (v2.w + v3.w);
    }
    for (; p < e; ++p) {
        int j = colIdx[p];
        float4 v = yin_r[(long)j * 8 + f4];
        ax += v.x; ay += v.y; az += v.z; aw += v.w;
    }
    hout[(long)node * 8 + f4] = elu4(make_float4(ax + b4.x + rv.x, ay + b4.y + rv.y,
                                                 az + b4.z + rv.z, aw + b4.w + rv.w));
}

// ---------------- mean pool + linear head + log_softmax ----------------
__global__ void pool_head(const float4* __restrict__ h4, const int* __restrict__ batch,
                          const float* __restrict__ Wlin, const float* __restrict__ blin,
                          float* __restrict__ out, int N) {
    int g = blockIdx.x;
    int lo = 0, hi = N;
    while (lo < hi) { int mid = (lo + hi) >> 1; if (batch[mid] < g) lo = mid + 1; else hi = mid; }
    int start = lo;
    hi = N;
    while (lo < hi) { int mid = (lo + hi) >> 1; if (batch[mid] < g + 1) lo = mid + 1; else hi = mid; }
    int end = lo;

    int f4 = threadIdx.x & 7, r = threadIdx.x >> 3;
    float4 acc = make_float4(0.f, 0.f, 0.f, 0.f);
    for (int i = start + r; i < end; i += 32) {
        float4 v = h4[(long)i * 8 + f4];
        acc.x += v.x; acc.y += v.y; acc.z += v.z; acc.w += v.w;
    }
    __shared__ float4 red[32][8];
    __shared__ float pooledS[32];
    red[r][f4] = acc;
    __syncthreads();
    if (r == 0) {
        float4 s = make_float4(0.f, 0.f, 0.f, 0.f);
#pragma unroll
        for (int r2 = 0; r2 < 32; ++r2) {
            float4 v = red[r2][f4];
            s.x += v.x; s.y += v.y; s.z += v.z; s.w += v.w;
        }
        float inv = 1.f / fmaxf((float)(end - start), 1.f);
        pooledS[f4 * 4 + 0] = s.x * inv;
        pooledS[f4 * 4 + 1] = s.y * inv;
        pooledS[f4 * 4 + 2] = s.z * inv;
        pooledS[f4 * 4 + 3] = s.w * inv;
    }
    __syncthreads();
    if (threadIdx.x == 0) {
        float c0 = blin[0], c1 = blin[1];
        for (int k = 0; k < 32; ++k) {
            float pk = pooledS[k];
            c0 += pk * Wlin[k * 2 + 0];
            c1 += pk * Wlin[k * 2 + 1];
        }
        float m = fmaxf(c0, c1);
        float lse = m + logf(expf(c0 - m) + expf(c1 - m));
        out[g * 2 + 0] = c0 - lse;
        out[g * 2 + 1] = c1 - lse;
    }
}

extern "C" void kernel_launch(void* const* d_in, const int* in_sizes, int n_in,
                              void* d_out, int out_size, void* d_ws, size_t ws_size,
                              hipStream_t stream) {
    const float* x     = (const float*)d_in[0];
    const int*   eidx  = (const int*)d_in[1];
    const int*   batch = (const int*)d_in[3];
    const float* W1r = (const float*)d_in[4];
    const float* W1l = (const float*)d_in[5];
    const float* b1  = (const float*)d_in[6];
    const float* W2r = (const float*)d_in[7];
    const float* W2l = (const float*)d_in[8];
    const float* b2  = (const float*)d_in[9];
    const float* W3r = (const float*)d_in[10];
    const float* W3l = (const float*)d_in[11];
    const float* b3  = (const float*)d_in[12];
    const float* Wlin = (const float*)d_in[13];
    const float* blin = (const float*)d_in[14];
    float* out = (float*)d_out;

    const int N = in_sizes[0] / D_IN;  // 50000
    const int E = in_sizes[1] / 2;     // 400000
    const int* src = eidx;
    const int* dst = eidx + E;

    char* w = (char*)d_ws;
    auto alloc = [&](size_t bytes) -> void* {
        void* p = (void*)w;
        w += (bytes + 255) & ~(size_t)255;
        return p;
    };
    int*   cnt     = (int*)alloc((size_t)N * 4);
    int*   row_ptr = (int*)alloc((size_t)(N + 1) * 4);
    int*   cursor  = (int*)alloc((size_t)(N + 1) * 4);
    int*   colIdx  = (int*)alloc((size_t)E * 4);
    int*   partial = (int*)alloc((size_t)256 * 4);
    __hip_bfloat16* Wt = (__hip_bfloat16*)alloc((size_t)WT_ELEMS * 2);
    float* yrA     = (float*)alloc((size_t)N * 32 * 4);
    float* ylA     = (float*)alloc((size_t)N * 32 * 4);
    float* yrB     = (float*)alloc((size_t)N * 32 * 4);
    float* ylB     = (float*)alloc((size_t)N * 32 * 4);
    float* hA      = (float*)alloc((size_t)N * 32 * 4);

    // --- CSR build + W prep ---
    hipMemsetAsync(cnt, 0, (size_t)N * 4, stream);
    int egrid = (E + 255) / 256;
    int sgrid = (N + SCAN_TILE - 1) / SCAN_TILE;
    count_edges<<<egrid, 256, 0, stream>>>(dst, cnt, E);
    scan_partial<<<sgrid, 256, 0, stream>>>(cnt, partial, N);
    scan_final<<<sgrid, 256, 0, stream>>>(cnt, partial, row_ptr, cursor, N);
    fill_csr<<<egrid, 256, 0, stream>>>(src, dst, cursor, colIdx, E);
    prep_w<<<(WT_ELEMS + 255) / 256, 256, 0, stream>>>(W1r, W1l, Wt);

    int ngrid64 = (N + 63) / 64;  // 782
    int ngrid32 = (N + 31) / 32;  // 1563

    // layer 1 (bf16 MFMA)
    gemm_mfma<<<ngrid64, 256, 0, stream>>>(x, Wt, yrA, ylA, N);
    agg_elu_k<<<ngrid32, 256, 0, stream>>>((const float4*)yrA, (const float4*)ylA,
                                           row_ptr, colIdx, b1, (float4*)hA, N);
    // layer 2 (fp32)
    gemm_xw<D_HID><<<ngrid32, 256, 0, stream>>>(hA, W2r, W2l, yrB, ylB, N);
    agg_elu_k<<<ngrid32, 256, 0, stream>>>((const float4*)yrB, (const float4*)ylB,
                                           row_ptr, colIdx, b2, (float4*)hA, N);
    // layer 3 (fp32)
    gemm_xw<D_HID><<<ngrid32, 256, 0, stream>>>(hA, W3r, W3l, yrA, ylA, N);
    agg_elu_k<<<ngrid32, 256, 0, stream>>>((const float4*)yrA, (const float4*)ylA,
                                           row_ptr, colIdx, b3, (float4*)hA, N);

    pool_head<<<N_GRAPHS, 256, 0, stream>>>((const float4*)hA, batch, Wlin, blin, out, N);
}

// Round 7
// 235.881 us; speedup vs baseline: 1.6004x; 1.0018x over previous
//
#include <hip/hip_runtime.h>
#include <hip/hip_bf16.h>

// GCN: 3x GraphConv(sum-agg) + ELU, mean-pool, linear head, log_softmax.
// N=50000, E=400000, G=64, D_IN=200, D_HID=32. fp32 inputs/outputs.
// segment_sum(x[src]) @ Wr == segment_sum((x@Wr)[src]) -> matmul first
// (200->32), aggregate 32-wide rows via CSR pull (no float atomics).
// R7: gemm_mfma goes LDS-free (A-frags read x directly from global -- the 4
// q-lanes of a row cover exactly one 128B line; B-frags from L2-hot packed Wt;
// no barrier, 8 waves/SIMD vs R6's 2). agg degree-loop: unroll-8 with masked
// fmaf tail (no serial remainder; 8 outstanding gathers per chain).

#define D_IN 200
#define D_HID 32
#define N_GRAPHS 64

#define KP 232            // padded K stride for bf16 Wt (200 -> pad 232)
#define KB 7              // 7 k-blocks of 32
#define WT_ELEMS (64 * KP)

#define SCAN_TILE 2048
#define SCAN_ITEMS 8

typedef __attribute__((ext_vector_type(8))) short bf16x8;
typedef __attribute__((ext_vector_type(4))) float f32x4;

// ---------------- CSR count + W1 pack (fused; independent block ranges) ------
__global__ void count_prep(const int* __restrict__ dst, int* __restrict__ cnt, int E,
                           const float* __restrict__ Wr, const float* __restrict__ Wl,
                           __hip_bfloat16* __restrict__ Wt, int egrid) {
    int blk = blockIdx.x;
    if (blk < egrid) {
        int e = blk * 256 + threadIdx.x;
        if (e < E) atomicAdd(&cnt[dst[e]], 1);
    } else {
        int idx = (blk - egrid) * 256 + threadIdx.x;
        if (idx < WT_ELEMS) {
            int n = idx / KP, k = idx % KP;
            float v = 0.f;
            if (k < D_IN) v = (n < 32) ? Wr[k * 32 + n] : Wl[k * 32 + (n - 32)];
            Wt[idx] = __float2bfloat16(v);
        }
    }
}

__global__ void scan_partial(const int* __restrict__ cnt, int* __restrict__ partial, int N) {
    __shared__ int sdata[256];
    int t = threadIdx.x;
    int base = blockIdx.x * SCAN_TILE + t * SCAN_ITEMS;
    int s = 0;
#pragma unroll
    for (int i = 0; i < SCAN_ITEMS; ++i) {
        int idx = base + i;
        if (idx < N) s += cnt[idx];
    }
    sdata[t] = s;
    __syncthreads();
    for (int off = 128; off > 0; off >>= 1) {
        if (t < off) sdata[t] += sdata[t + off];
        __syncthreads();
    }
    if (t == 0) partial[blockIdx.x] = sdata[0];
}

__global__ void scan_final(const int* __restrict__ cnt, const int* __restrict__ partial,
                           int* __restrict__ row_ptr, int* __restrict__ cursor, int N) {
    __shared__ int sdata[256];
    __shared__ int blockOff;
    int t = threadIdx.x;
    if (t == 0) {
        int run = 0;
        for (int i = 0; i < (int)blockIdx.x; ++i) run += partial[i];
        blockOff = run;
    }
    int base = blockIdx.x * SCAN_TILE + t * SCAN_ITEMS;
    int vals[SCAN_ITEMS];
    int s = 0;
#pragma unroll
    for (int i = 0; i < SCAN_ITEMS; ++i) {
        int idx = base + i;
        vals[i] = (idx < N) ? cnt[idx] : 0;
        s += vals[i];
    }
    sdata[t] = s;
    __syncthreads();
    int sum = s;
    for (int off = 1; off < 256; off <<= 1) {
        int v = (t >= off) ? sdata[t - off] : 0;
        __syncthreads();
        sdata[t] += v;
        __syncthreads();
    }
    int run = blockOff + sdata[t] - sum;
#pragma unroll
    for (int i = 0; i < SCAN_ITEMS; ++i) {
        int idx = base + i;
        if (idx < N) { row_ptr[idx] = run; cursor[idx] = run; run += vals[i]; }
    }
    if (blockIdx.x == gridDim.x - 1 && t == 255) row_ptr[N] = blockOff + sdata[255];
}

__global__ void fill_csr(const int* __restrict__ src, const int* __restrict__ dst,
                         int* __restrict__ cursor, int* __restrict__ colIdx, int E) {
    int e = blockIdx.x * blockDim.x + threadIdx.x;
    if (e < E) {
        int p = atomicAdd(&cursor[dst[e]], 1);
        colIdx[p] = src[e];
    }
}

// ---------------- layer-1 GEMM via MFMA, LDS-free ----------------
// 64 nodes/block, 4 waves (wv -> rows wv*16..+15). Lane l: A row = l&15,
// k = (l>>4)*8+j. A loaded straight from global fp32 (32B/lane; the 4 q-lanes
// of a row = one 128B line), cvt to bf16 in-register. B from packed Wt
// ([64][KP] bf16, zero-padded) -- L2-hot. C/D: col=lane&15, row=q*4+reg.
__global__ __launch_bounds__(256) void gemm_mfma(const float* __restrict__ X,
                                                 const __hip_bfloat16* __restrict__ Wt,
                                                 float* __restrict__ yr,
                                                 float* __restrict__ yl, int N) {
    int t = threadIdx.x;
    int lane = t & 63;
    int wv = t >> 6;
    int l15 = lane & 15, q = lane >> 4;
    long base = (long)blockIdx.x * 64;
    long row = base + wv * 16 + l15;
    long rowc = (row < (long)N) ? row : (long)(N - 1);
    const float* xr = X + rowc * D_IN;

    bf16x8 a[KB];
#pragma unroll
    for (int kb = 0; kb < KB; ++kb) {
        int k0 = kb * 32 + q * 8;
        union { __hip_bfloat16 h[8]; bf16x8 v; } u;
        if (k0 + 8 <= D_IN) {           // always true for kb<6; kb==6 only q==0
            float4 v0 = *(const float4*)(xr + k0);
            float4 v1 = *(const float4*)(xr + k0 + 4);
            u.h[0] = __float2bfloat16(v0.x); u.h[1] = __float2bfloat16(v0.y);
            u.h[2] = __float2bfloat16(v0.z); u.h[3] = __float2bfloat16(v0.w);
            u.h[4] = __float2bfloat16(v1.x); u.h[5] = __float2bfloat16(v1.y);
            u.h[6] = __float2bfloat16(v1.z); u.h[7] = __float2bfloat16(v1.w);
        } else {
#pragma unroll
            for (int j = 0; j < 8; ++j) {
                int k = k0 + j;
                u.h[j] = __float2bfloat16(k < D_IN ? xr[k] : 0.f);
            }
        }
        a[kb] = u.v;
    }

#pragma unroll
    for (int ns = 0; ns < 4; ++ns) {
        f32x4 acc = {0.f, 0.f, 0.f, 0.f};
#pragma unroll
        for (int kb = 0; kb < KB; ++kb) {
            bf16x8 b = *(const bf16x8*)(const void*)(Wt + (ns * 16 + l15) * KP + kb * 32 + q * 8);
            acc = __builtin_amdgcn_mfma_f32_16x16x32_bf16(a[kb], b, acc, 0, 0, 0);
        }
        int col = ns * 16 + l15;
        float* Y = (col < 32) ? yr : yl;
        int cc = col & 31;
#pragma unroll
        for (int r = 0; r < 4; ++r) {
            long node = base + wv * 16 + q * 4 + r;
            if (node < N) Y[node * 32 + cc] = acc[r];
        }
    }
}

// ---------------- fp32 GEMM (K=32) for layers 2,3 ----------------
template <int K>
__global__ __launch_bounds__(256) void gemm_xw(const float* __restrict__ X,
                                               const float* __restrict__ Wr,
                                               const float* __restrict__ Wl,
                                               float* __restrict__ yr, float* __restrict__ yl,
                                               int N) {
    constexpr int K4 = K / 4;
    __shared__ float4 xs[32 * K4];
    int t = threadIdx.x;
    long base = (long)blockIdx.x * 32;
    const float4* X4 = (const float4*)X;
    long total4 = (long)N * K4;
    long g0 = base * K4;
    for (int i = t; i < 32 * K4; i += 256) {
        long gi = g0 + i;
        xs[i] = (gi < total4) ? X4[gi] : make_float4(0.f, 0.f, 0.f, 0.f);
    }
    __syncthreads();

    int c = t & 31;
    int nb = (t >> 5) * 4;
    float accr[4] = {0.f, 0.f, 0.f, 0.f};
    float accl[4] = {0.f, 0.f, 0.f, 0.f};
    for (int k4 = 0; k4 < K4; ++k4) {
        float wr[4], wl[4];
#pragma unroll
        for (int qq = 0; qq < 4; ++qq) {
            wr[qq] = Wr[(k4 * 4 + qq) * 32 + c];
            wl[qq] = Wl[(k4 * 4 + qq) * 32 + c];
        }
#pragma unroll
        for (int i = 0; i < 4; ++i) {
            float4 xv = xs[(nb + i) * K4 + k4];
            accr[i] = fmaf(xv.x, wr[0], accr[i]); accr[i] = fmaf(xv.y, wr[1], accr[i]);
            accr[i] = fmaf(xv.z, wr[2], accr[i]); accr[i] = fmaf(xv.w, wr[3], accr[i]);
            accl[i] = fmaf(xv.x, wl[0], accl[i]); accl[i] = fmaf(xv.y, wl[1], accl[i]);
            accl[i] = fmaf(xv.z, wl[2], accl[i]); accl[i] = fmaf(xv.w, wl[3], accl[i]);
        }
    }
#pragma unroll
    for (int i = 0; i < 4; ++i) {
        long node = base + nb + i;
        if (node < N) {
            yr[node * 32 + c] = accr[i];
            yl[node * 32 + c] = accl[i];
        }
    }
}

__device__ __forceinline__ float4 elu4(float4 v) {
    float4 o;
    o.x = (v.x > 0.f) ? v.x : expm1f(v.x);
    o.y = (v.y > 0.f) ? v.y : expm1f(v.y);
    o.z = (v.z > 0.f) ? v.z : expm1f(v.z);
    o.w = (v.w > 0.f) ? v.w : expm1f(v.w);
    return o;
}

// ---------------- aggregate (CSR pull) + bias + root + ELU -------------------
// 8 lanes/node (float4 each). Degree loop: unroll-8, remainder-free via
// clamped index + fmaf mask (exact: fmaf(v,0,a)==a). 8 outstanding gathers
// per chain; rounds = ceil(deg/8) ~ 1-2 at avg degree 8.
__global__ __launch_bounds__(256) void agg_elu_k(const float4* __restrict__ yin_r,
                                                 const float4* __restrict__ yin_l,
                                                 const int* __restrict__ row_ptr,
                                                 const int* __restrict__ colIdx,
                                                 const float* __restrict__ b,
                                                 float4* __restrict__ hout, int N) {
    int t = threadIdx.x;
    int f4 = t & 7;
    int node = blockIdx.x * 32 + (t >> 3);
    if (node >= N) return;
    int s = row_ptr[node], e = row_ptr[node + 1];
    float4 b4 = ((const float4*)b)[f4];
    float4 rv = yin_l[(long)node * 8 + f4];
    float ax = 0.f, ay = 0.f, az = 0.f, aw = 0.f;
    for (int p = s; p < e; p += 8) {
        int jj[8]; float m[8];
#pragma unroll
        for (int i = 0; i < 8; ++i) {
            int pi = p + i;
            m[i] = (pi < e) ? 1.f : 0.f;
            pi = (pi < e) ? pi : (e - 1);   // clamped: duplicate load, masked out
            jj[i] = colIdx[pi];
        }
        float4 v[8];
#pragma unroll
        for (int i = 0; i < 8; ++i) v[i] = yin_r[(long)jj[i] * 8 + f4];
#pragma unroll
        for (int i = 0; i < 8; ++i) {
            ax = fmaf(v[i].x, m[i], ax);
            ay = fmaf(v[i].y, m[i], ay);
            az = fmaf(v[i].z, m[i], az);
            aw = fmaf(v[i].w, m[i], aw);
        }
    }
    hout[(long)node * 8 + f4] = elu4(make_float4(ax + b4.x + rv.x, ay + b4.y + rv.y,
                                                 az + b4.z + rv.z, aw + b4.w + rv.w));
}

// ---------------- mean pool + linear head + log_softmax ----------------
__global__ void pool_head(const float4* __restrict__ h4, const int* __restrict__ batch,
                          const float* __restrict__ Wlin, const float* __restrict__ blin,
                          float* __restrict__ out, int N) {
    int g = blockIdx.x;
    int lo = 0, hi = N;
    while (lo < hi) { int mid = (lo + hi) >> 1; if (batch[mid] < g) lo = mid + 1; else hi = mid; }
    int start = lo;
    hi = N;
    while (lo < hi) { int mid = (lo + hi) >> 1; if (batch[mid] < g + 1) lo = mid + 1; else hi = mid; }
    int end = lo;

    int f4 = threadIdx.x & 7, r = threadIdx.x >> 3;
    float4 acc = make_float4(0.f, 0.f, 0.f, 0.f);
    for (int i = start + r; i < end; i += 32) {
        float4 v = h4[(long)i * 8 + f4];
        acc.x += v.x; acc.y += v.y; acc.z += v.z; acc.w += v.w;
    }
    __shared__ float4 red[32][8];
    __shared__ float pooledS[32];
    red[r][f4] = acc;
    __syncthreads();
    if (r == 0) {
        float4 s = make_float4(0.f, 0.f, 0.f, 0.f);
#pragma unroll
        for (int r2 = 0; r2 < 32; ++r2) {
            float4 v = red[r2][f4];
            s.x += v.x; s.y += v.y; s.z += v.z; s.w += v.w;
        }
        float inv = 1.f / fmaxf((float)(end - start), 1.f);
        pooledS[f4 * 4 + 0] = s.x * inv;
        pooledS[f4 * 4 + 1] = s.y * inv;
        pooledS[f4 * 4 + 2] = s.z * inv;
        pooledS[f4 * 4 + 3] = s.w * inv;
    }
    __syncthreads();
    if (threadIdx.x == 0) {
        float c0 = blin[0], c1 = blin[1];
        for (int k = 0; k < 32; ++k) {
            float pk = pooledS[k];
            c0 += pk * Wlin[k * 2 + 0];
            c1 += pk * Wlin[k * 2 + 1];
        }
        float m = fmaxf(c0, c1);
        float lse = m + logf(expf(c0 - m) + expf(c1 - m));
        out[g * 2 + 0] = c0 - lse;
        out[g * 2 + 1] = c1 - lse;
    }
}

extern "C" void kernel_launch(void* const* d_in, const int* in_sizes, int n_in,
                              void* d_out, int out_size, void* d_ws, size_t ws_size,
                              hipStream_t stream) {
    const float* x     = (const float*)d_in[0];
    const int*   eidx  = (const int*)d_in[1];
    const int*   batch = (const int*)d_in[3];
    const float* W1r = (const float*)d_in[4];
    const float* W1l = (const float*)d_in[5];
    const float* b1  = (const float*)d_in[6];
    const float* W2r = (const float*)d_in[7];
    const float* W2l = (const float*)d_in[8];
    const float* b2  = (const float*)d_in[9];
    const float* W3r = (const float*)d_in[10];
    const float* W3l = (const float*)d_in[11];
    const float* b3  = (const float*)d_in[12];
    const float* Wlin = (const float*)d_in[13];
    const float* blin = (const float*)d_in[14];
    float* out = (float*)d_out;

    const int N = in_sizes[0] / D_IN;  // 50000
    const int E = in_sizes[1] / 2;     // 400000
    const int* src = eidx;
    const int* dst = eidx + E;

    char* w = (char*)d_ws;
    auto alloc = [&](size_t bytes) -> void* {
        void* p = (void*)w;
        w += (bytes + 255) & ~(size_t)255;
        return p;
    };
    int*   cnt     = (int*)alloc((size_t)N * 4);
    int*   row_ptr = (int*)alloc((size_t)(N + 1) * 4);
    int*   cursor  = (int*)alloc((size_t)(N + 1) * 4);
    int*   colIdx  = (int*)alloc((size_t)E * 4);
    int*   partial = (int*)alloc((size_t)256 * 4);
    __hip_bfloat16* Wt = (__hip_bfloat16*)alloc((size_t)WT_ELEMS * 2);
    float* yrA     = (float*)alloc((size_t)N * 32 * 4);
    float* ylA     = (float*)alloc((size_t)N * 32 * 4);
    float* yrB     = (float*)alloc((size_t)N * 32 * 4);
    float* ylB     = (float*)alloc((size_t)N * 32 * 4);
    float* hA      = (float*)alloc((size_t)N * 32 * 4);

    // --- CSR build + W prep ---
    hipMemsetAsync(cnt, 0, (size_t)N * 4, stream);
    int egrid = (E + 255) / 256;
    int wgrid = (WT_ELEMS + 255) / 256;
    int sgrid = (N + SCAN_TILE - 1) / SCAN_TILE;
    count_prep<<<egrid + wgrid, 256, 0, stream>>>(dst, cnt, E, W1r, W1l, Wt, egrid);
    scan_partial<<<sgrid, 256, 0, stream>>>(cnt, partial, N);
    scan_final<<<sgrid, 256, 0, stream>>>(cnt, partial, row_ptr, cursor, N);
    fill_csr<<<egrid, 256, 0, stream>>>(src, dst, cursor, colIdx, E);

    int ngrid64 = (N + 63) / 64;  // 782
    int ngrid32 = (N + 31) / 32;  // 1563

    // layer 1 (bf16 MFMA, LDS-free)
    gemm_mfma<<<ngrid64, 256, 0, stream>>>(x, Wt, yrA, ylA, N);
    agg_elu_k<<<ngrid32, 256, 0, stream>>>((const float4*)yrA, (const float4*)ylA,
                                           row_ptr, colIdx, b1, (float4*)hA, N);
    // layer 2 (fp32)
    gemm_xw<D_HID><<<ngrid32, 256, 0, stream>>>(hA, W2r, W2l, yrB, ylB, N);
    agg_elu_k<<<ngrid32, 256, 0, stream>>>((const float4*)yrB, (const float4*)ylB,
                                           row_ptr, colIdx, b2, (float4*)hA, N);
    // layer 3 (fp32)
    gemm_xw<D_HID><<<ngrid32, 256, 0, stream>>>(hA, W3r, W3l, yrA, ylA, N);
    agg_elu_k<<<ngrid32, 256, 0, stream>>>((const float4*)yrA, (const float4*)ylA,
                                           row_ptr, colIdx, b3, (float4*)hA, N);

    pool_head<<<N_GRAPHS, 256, 0, stream>>>((const float4*)hA, batch, Wlin, blin, out, N);
}